// Round 9
// baseline (357.697 us; speedup 1.0000x reference)
//
#include <hip/hip_runtime.h>

typedef __attribute__((ext_vector_type(8))) short bf16x8;
typedef __attribute__((ext_vector_type(4))) float f32x4;

__device__ __forceinline__ unsigned short f2bf(float f) {  // RNE
  unsigned u = __float_as_uint(f);
  u += 0x7FFFu + ((u >> 16) & 1u);
  return (unsigned short)(u >> 16);
}
__device__ __forceinline__ float bflo(unsigned u) { return __uint_as_float(u << 16); }
__device__ __forceinline__ float bfhi(unsigned u) { return __uint_as_float(u & 0xFFFF0000u); }

// ---------------- MFMA bf16 GEMM body (m89/m91-verified layouts) ----------------
// A: m=lane&15, k=quad*8+j   B: n=lane&15, k=quad*8+j   D: col=lane&15, row=quad*4+reg
__device__ __forceinline__ void gemm1_body(const float* __restrict__ A0,
                                           const float* __restrict__ W,
                                           unsigned short* __restrict__ Y, int N,
                                           int bid, int tid, unsigned short* Wl) {
  constexpr int K = 128, CO = 128;
  constexpr int SP = K + 8;
  for (int i = tid; i < K * CO; i += 256) {
    int k = i / CO, n = i % CO;
    Wl[n * SP + k] = f2bf(W[i]);
  }
  __syncthreads();

  const int lane = tid & 63;
  const int quad = lane >> 4, l16 = lane & 15;
  const int mbase = bid * 64 + (tid >> 6) * 16;
  const int arow = min(mbase + l16, N - 1);

  bf16x8 afrag[4];
  const float* A = A0 + (size_t)arow * K;
#pragma unroll
  for (int ks = 0; ks < 4; ks++) {
    const float4* p = (const float4*)(A + ks * 32 + quad * 8);
    float4 f0 = p[0], f1 = p[1];
    afrag[ks] = (bf16x8){(short)f2bf(f0.x), (short)f2bf(f0.y), (short)f2bf(f0.z), (short)f2bf(f0.w),
                         (short)f2bf(f1.x), (short)f2bf(f1.y), (short)f2bf(f1.z), (short)f2bf(f1.w)};
  }

#pragma unroll
  for (int ct = 0; ct < CO / 16; ct++) {
    f32x4 acc = {0.0f, 0.0f, 0.0f, 0.0f};
#pragma unroll
    for (int ks = 0; ks < 4; ks++) {
      bf16x8 b = *(const bf16x8*)(&Wl[(ct * 16 + l16) * SP + ks * 32 + quad * 8]);
      acc = __builtin_amdgcn_mfma_f32_16x16x32_bf16(afrag[ks], b, acc, 0, 0, 0);
    }
#pragma unroll
    for (int reg = 0; reg < 4; reg++) {
      int node = mbase + quad * 4 + reg;
      if (node < N) Y[(size_t)node * CO + ct * 16 + l16] = f2bf(acc[reg]);
    }
  }
}

// ---------------- pre: edge histogram | batch first-occurrence ----------------
__global__ __launch_bounds__(256) void k_pre(const int* __restrict__ dst,
                                             int* __restrict__ cnt, int E,
                                             const int* __restrict__ batch,
                                             int* __restrict__ firstIdx, int N, int gE) {
  const int bid = blockIdx.x, tid = threadIdx.x;
  if (bid < gE) {
    int e = bid * 256 + tid;
    if (e < E) atomicAdd(&cnt[dst[e]], 1);
  } else {
    int n = (bid - gE) * 256 + tid;
    if (n < N) {
      int b = batch[n];
      if (n == 0 || batch[n - 1] != b) firstIdx[b] = n + 1;  // +1-encoded
    }
  }
}

// ---------------- segment allocation (order-free) ----------------
__global__ void k_seg(const int* __restrict__ cnt, int* __restrict__ start,
                      int* __restrict__ cursor, float* __restrict__ dinv,
                      int* __restrict__ counter, int N) {
  const int v = blockIdx.x * 256 + threadIdx.x;
  const int lane = threadIdx.x & 63;
  int cn = (v < N) ? cnt[v] : 0;
  int incl = cn;
#pragma unroll
  for (int d = 1; d < 64; d <<= 1) {
    int t = __shfl_up(incl, d, 64);
    if (lane >= d) incl += t;
  }
  int base = 0;
  if (lane == 63) base = atomicAdd(counter, incl);
  base = __shfl(base, 63, 64);
  if (v < N) {
    int s = base + incl - cn;
    start[v] = s;
    cursor[v] = s;
    dinv[v] = rsqrtf((float)(cn + 1));  // +1 self-loop
  }
}

// ---------------- mega: GEMM1 blocks || edge-fill blocks (independent work) --------
__global__ __launch_bounds__(256) void k_mega(const float* __restrict__ x,
                                              const float* __restrict__ W1,
                                              unsigned short* __restrict__ xw1b, int N,
                                              const int* __restrict__ src,
                                              const int* __restrict__ dst,
                                              int* __restrict__ cursor,
                                              int* __restrict__ col, int E, int gM) {
  __shared__ unsigned short Wl[128 * 136];
  const int bid = blockIdx.x, tid = threadIdx.x;
  if (bid < gM) {
    gemm1_body(x, W1, xw1b, N, bid, tid, Wl);
  } else {
    const int stride = (gridDim.x - gM) * 256;
    for (int e = (bid - gM) * 256 + tid; e < E; e += stride) {
      int d = dst[e];
      int p = atomicAdd(&cursor[d], 1);
      col[p] = src[e];
    }
  }
}

// ---------------- layer-1 aggregate: lane-prefetched edges, bf16 rows ----------------
__global__ __launch_bounds__(256) void k_agg128(const unsigned short* __restrict__ xwb,
                                                const float* __restrict__ dinv,
                                                const int* __restrict__ start,
                                                const int* __restrict__ cnt,
                                                const int* __restrict__ col,
                                                const float* __restrict__ bias,
                                                unsigned short* __restrict__ out, int N) {
  const int lane = threadIdx.x & 63;
  const int v = blockIdx.x * 4 + (threadIdx.x >> 6);
  if (v >= N) return;
  const float dv = dinv[v];
  unsigned u = ((const unsigned*)(xwb + (size_t)v * 128))[lane];
  float ax = dv * dv * bflo(u);
  float ay = dv * dv * bfhi(u);
  const int j0 = start[v], jc = cnt[v];
  for (int base = 0; base < jc; base += 64) {
    int sl = (base + lane < jc) ? col[j0 + base + lane] : 0;
    float dl = dinv[sl];
    const int m = min(64, jc - base);
#pragma unroll 8
    for (int t = 0; t < m; t++) {
      int s = __shfl(sl, t, 64);
      float w = __shfl(dl, t, 64) * dv;
      unsigned r = ((const unsigned*)(xwb + (size_t)s * 128))[lane];
      ax += w * bflo(r);
      ay += w * bfhi(r);
    }
  }
  float2 b = ((const float2*)bias)[lane];
  ax = fmaxf(ax + b.x, 0.0f);
  ay = fmaxf(ay + b.y, 0.0f);
  ((unsigned*)(out + (size_t)v * 128))[lane] =
      (unsigned)f2bf(ax) | ((unsigned)f2bf(ay) << 16);
}

// ---------------- second aggregate on h1 fused with pooling (8-way stage) ----------
__global__ __launch_bounds__(256) void k_aggpool128(const unsigned short* __restrict__ h1b,
                                                    const float* __restrict__ dinv,
                                                    const int* __restrict__ start,
                                                    const int* __restrict__ cnt,
                                                    const int* __restrict__ col,
                                                    const int* __restrict__ batch,
                                                    float* __restrict__ stage, int N) {
  __shared__ float2 red[256];
  const int lane = threadIdx.x & 63;
  const int wv = threadIdx.x >> 6;
  const int v = blockIdx.x * 4 + wv;
  float ax = 0.0f, ay = 0.0f;
  if (v < N) {
    const float dv = dinv[v];
    unsigned u = ((const unsigned*)(h1b + (size_t)v * 128))[lane];
    ax = dv * dv * bflo(u);
    ay = dv * dv * bfhi(u);
    const int j0 = start[v], jc = cnt[v];
    for (int base = 0; base < jc; base += 64) {
      int sl = (base + lane < jc) ? col[j0 + base + lane] : 0;
      float dl = dinv[sl];
      const int m = min(64, jc - base);
#pragma unroll 8
      for (int t = 0; t < m; t++) {
        int s = __shfl(sl, t, 64);
        float w = __shfl(dl, t, 64) * dv;
        unsigned r = ((const unsigned*)(h1b + (size_t)s * 128))[lane];
        ax += w * bflo(r);
        ay += w * bfhi(r);
      }
    }
  }
  red[threadIdx.x] = make_float2(ax, ay);
  __syncthreads();
  float* st = stage + (size_t)(blockIdx.x & 7) * 64 * 128;  // 8 replicated copies
  const int v0 = blockIdx.x * 4;
  const int b0 = batch[min(v0, N - 1)];
  const int b3 = batch[min(v0 + 3, N - 1)];
  if ((b0 == b3) && (v0 + 3 < N)) {          // sorted batch -> block-uniform graph
    if (wv == 0) {
      float2 r0 = red[lane], r1 = red[64 + lane], r2 = red[128 + lane], r3 = red[192 + lane];
      atomicAdd(&st[b0 * 128 + 2 * lane], r0.x + r1.x + r2.x + r3.x);
      atomicAdd(&st[b0 * 128 + 2 * lane + 1], r0.y + r1.y + r2.y + r3.y);
    }
  } else if (v < N) {
    int b = batch[v];
    atomicAdd(&st[b * 128 + 2 * lane], ax);
    atomicAdd(&st[b * 128 + 2 * lane + 1], ay);
  }
}

// reduce 8 stage copies -> pooled[64*128]
__global__ void k_sreduce(const float* __restrict__ stage, float* __restrict__ pooled) {
  int i = blockIdx.x * 256 + threadIdx.x;  // 8192 total
  float s = 0.0f;
#pragma unroll
  for (int k = 0; k < 8; k++) s += stage[k * 8192 + i];
  pooled[i] = s;
}

// ---------------- final: counts; out = (pooled/n) @ W2 + b2 ----------------
__global__ void k_final(const float* __restrict__ pooled, const int* __restrict__ firstIdx,
                        const float* __restrict__ W2, const float* __restrict__ b2,
                        float* __restrict__ out, int N) {
  __shared__ float rinv[64];
  const int tid = threadIdx.x;
  if (tid < 64) {
    int raw = firstIdx[tid];
    int fi = (raw > 0) ? raw - 1 : 0x7FFFFFFF;
    int m = fi;
#pragma unroll
    for (int d = 1; d < 64; d <<= 1) {
      int t = __shfl_down(m, d, 64);
      if (tid + d < 64) m = min(m, t);
    }
    int nxtm = __shfl_down(m, 1, 64);           // min first-idx over graphs > tid
    int nxt = (tid == 63) ? N : min(nxtm, N);
    int cgt = (fi == 0x7FFFFFFF) ? 0 : (nxt - fi);
    rinv[tid] = 1.0f / fmaxf((float)cgt, 1.0f);
  }
  __syncthreads();
  const int g = tid >> 2;        // 64 graphs
  const int jg = tid & 3;        // 4 groups of 16 outputs
  float acc[16];
#pragma unroll
  for (int i = 0; i < 16; i++) acc[i] = 0.f;
  for (int f = 0; f < 128; f++) {
    float p = pooled[g * 128 + f];
#pragma unroll
    for (int i = 0; i < 16; i++) acc[i] += p * W2[f * 64 + jg * 16 + i];
  }
  float r = rinv[g];
#pragma unroll
  for (int i = 0; i < 16; i++)
    out[g * 64 + jg * 16 + i] = r * acc[i] + b2[jg * 16 + i];
}

// ---------------- launch ----------------

extern "C" void kernel_launch(void* const* d_in, const int* in_sizes, int n_in,
                              void* d_out, int out_size, void* d_ws, size_t ws_size,
                              hipStream_t stream) {
  const float* x     = (const float*)d_in[0];
  const int*   ei    = (const int*)d_in[1];
  const int*   batch = (const int*)d_in[2];
  const float* W1    = (const float*)d_in[3];
  const float* b1    = (const float*)d_in[4];
  const float* W2    = (const float*)d_in[5];
  const float* b2    = (const float*)d_in[6];

  const int N = in_sizes[2];       // 50000
  const int E = in_sizes[1] / 2;   // 800000
  const int* src  = ei;
  const int* dstv = ei + E;

  // workspace layout
  unsigned short* xw1b = (unsigned short*)d_ws;      // N*128 bf16
  unsigned short* h1b  = xw1b + (size_t)N * 128;     // N*128 bf16
  // zero region: cnt[N] counter[1] firstIdx[64] stage[8*64*128]
  int*   cnt      = (int*)(h1b + (size_t)N * 128);
  int*   counter  = cnt + N;
  int*   firstIdx = counter + 1;
  float* stage    = (float*)(firstIdx + 64);         // 8 copies of 64*128
  const size_t zero_ints = (size_t)N + 1 + 64 + 8 * 64 * 128;
  // non-zeroed scratch
  float* pooled   = stage + 8 * 64 * 128;            // 64*128
  int*   startv   = (int*)(pooled + 64 * 128);       // N
  int*   cursor   = startv + N;                      // N
  float* dinv     = (float*)(cursor + N);            // N
  int*   col      = (int*)(dinv + N);                // E
  float* outp     = (float*)d_out;                   // 64*64

  hipMemsetAsync(cnt, 0, zero_ints * sizeof(int), stream);

  const int gM = (N + 63) / 64;     // 782
  const int gE = (E + 255) / 256;   // 3125
  const int gN = (N + 255) / 256;   // 196
  const int gA = (N + 3) / 4;       // 12500
  const int gF = 1024;              // fill blocks inside mega

  k_pre<<<gE + gN, 256, 0, stream>>>(dstv, cnt, E, batch, firstIdx, N, gE);
  k_seg<<<gN, 256, 0, stream>>>(cnt, startv, cursor, dinv, counter, N);

  // GEMM1 overlapped with edge-fill (independent after seg)
  k_mega<<<gM + gF, 256, 0, stream>>>(x, W1, xw1b, N, src, dstv, cursor, col, E, gM);

  // layer 1 aggregate (+bias+relu)
  k_agg128<<<gA, 256, 0, stream>>>(xw1b, dinv, startv, cnt, col, b1, h1b, N);

  // layer 2 commuted: stage[g] = sum_{v in g} Agg(h1)[v]; then (pooled/n) @ W2 + b2
  k_aggpool128<<<gA, 256, 0, stream>>>(h1b, dinv, startv, cnt, col, batch, stage, N);
  k_sreduce<<<32, 256, 0, stream>>>(stage, pooled);
  k_final<<<1, 256, 0, stream>>>(pooled, firstIdx, W2, b2, outp, N);
}

// Round 10
// 324.231 us; speedup vs baseline: 1.1032x; 1.1032x over previous
//
#include <hip/hip_runtime.h>

typedef __attribute__((ext_vector_type(8))) short bf16x8;
typedef __attribute__((ext_vector_type(4))) float f32x4;

__device__ __forceinline__ unsigned short f2bf(float f) {  // RNE
  unsigned u = __float_as_uint(f);
  u += 0x7FFFu + ((u >> 16) & 1u);
  return (unsigned short)(u >> 16);
}
__device__ __forceinline__ float bflo(unsigned u) { return __uint_as_float(u << 16); }
__device__ __forceinline__ float bfhi(unsigned u) { return __uint_as_float(u & 0xFFFF0000u); }

// ---------------- MFMA bf16 GEMM body (m89/m91-verified layouts) ----------------
// A: m=lane&15, k=quad*8+j   B: n=lane&15, k=quad*8+j   D: col=lane&15, row=quad*4+reg
__device__ __forceinline__ void gemm1_body(const float* __restrict__ A0,
                                           const float* __restrict__ W,
                                           unsigned short* __restrict__ Y, int N,
                                           int bid, int tid, unsigned short* Wl) {
  constexpr int K = 128, CO = 128;
  constexpr int SP = K + 8;
  for (int i = tid; i < K * CO; i += 256) {
    int k = i / CO, n = i % CO;
    Wl[n * SP + k] = f2bf(W[i]);
  }
  __syncthreads();

  const int lane = tid & 63;
  const int quad = lane >> 4, l16 = lane & 15;
  const int mbase = bid * 64 + (tid >> 6) * 16;
  const int arow = min(mbase + l16, N - 1);

  bf16x8 afrag[4];
  const float* A = A0 + (size_t)arow * K;
#pragma unroll
  for (int ks = 0; ks < 4; ks++) {
    const float4* p = (const float4*)(A + ks * 32 + quad * 8);
    float4 f0 = p[0], f1 = p[1];
    afrag[ks] = (bf16x8){(short)f2bf(f0.x), (short)f2bf(f0.y), (short)f2bf(f0.z), (short)f2bf(f0.w),
                         (short)f2bf(f1.x), (short)f2bf(f1.y), (short)f2bf(f1.z), (short)f2bf(f1.w)};
  }

#pragma unroll
  for (int ct = 0; ct < CO / 16; ct++) {
    f32x4 acc = {0.0f, 0.0f, 0.0f, 0.0f};
#pragma unroll
    for (int ks = 0; ks < 4; ks++) {
      bf16x8 b = *(const bf16x8*)(&Wl[(ct * 16 + l16) * SP + ks * 32 + quad * 8]);
      acc = __builtin_amdgcn_mfma_f32_16x16x32_bf16(afrag[ks], b, acc, 0, 0, 0);
    }
#pragma unroll
    for (int reg = 0; reg < 4; reg++) {
      int node = mbase + quad * 4 + reg;
      if (node < N) Y[(size_t)node * CO + ct * 16 + l16] = f2bf(acc[reg]);
    }
  }
}

// ---------------- pre: edge histogram | batch first-occurrence ----------------
__global__ __launch_bounds__(256) void k_pre(const int* __restrict__ dst,
                                             int* __restrict__ cnt, int E,
                                             const int* __restrict__ batch,
                                             int* __restrict__ firstIdx, int N, int gE) {
  const int bid = blockIdx.x, tid = threadIdx.x;
  if (bid < gE) {
    int e = bid * 256 + tid;
    if (e < E) atomicAdd(&cnt[dst[e]], 1);
  } else {
    int n = (bid - gE) * 256 + tid;
    if (n < N) {
      int b = batch[n];
      if (n == 0 || batch[n - 1] != b) firstIdx[b] = n + 1;  // +1-encoded
    }
  }
}

// ---------------- segment allocation (order-free) ----------------
__global__ void k_seg(const int* __restrict__ cnt, int* __restrict__ start,
                      int* __restrict__ cursor, float* __restrict__ dinv,
                      int* __restrict__ counter, int N) {
  const int v = blockIdx.x * 256 + threadIdx.x;
  const int lane = threadIdx.x & 63;
  int cn = (v < N) ? cnt[v] : 0;
  int incl = cn;
#pragma unroll
  for (int d = 1; d < 64; d <<= 1) {
    int t = __shfl_up(incl, d, 64);
    if (lane >= d) incl += t;
  }
  int base = 0;
  if (lane == 63) base = atomicAdd(counter, incl);
  base = __shfl(base, 63, 64);
  if (v < N) {
    int s = base + incl - cn;
    start[v] = s;
    cursor[v] = s;
    dinv[v] = rsqrtf((float)(cn + 1));  // +1 self-loop
  }
}

// ---------------- mega: GEMM1 blocks || edge-fill blocks (independent work) --------
__global__ __launch_bounds__(256) void k_mega(const float* __restrict__ x,
                                              const float* __restrict__ W1,
                                              unsigned short* __restrict__ xw1b, int N,
                                              const int* __restrict__ src,
                                              const int* __restrict__ dst,
                                              int* __restrict__ cursor,
                                              int* __restrict__ col, int E, int gM) {
  __shared__ unsigned short Wl[128 * 136];
  const int bid = blockIdx.x, tid = threadIdx.x;
  if (bid < gM) {
    gemm1_body(x, W1, xw1b, N, bid, tid, Wl);
  } else {
    const int stride = (gridDim.x - gM) * 256;
    for (int e = (bid - gM) * 256 + tid; e < E; e += stride) {
      int d = dst[e];
      int p = atomicAdd(&cursor[d], 1);
      col[p] = src[e];
    }
  }
}

// ---------------- batched-MLP gather core: 8 row-loads in flight ----------------
// loads issued into rr[8] before any FMA -> 8 outstanding global loads per wave
#define GATHER_LOOP(TBL)                                                         \
  for (int base = 0; base < jc; base += 64) {                                    \
    int sl = (base + lane < jc) ? col[j0 + base + lane] : 0;                     \
    float dl = dinv[sl] * dv;                                                    \
    const int m = min(64, jc - base);                                            \
    int t = 0;                                                                   \
    for (; t + 8 <= m; t += 8) {                                                 \
      unsigned rr[8]; float ww[8];                                               \
      _Pragma("unroll")                                                          \
      for (int i = 0; i < 8; i++) {                                              \
        int s = __shfl(sl, t + i, 64);                                           \
        ww[i] = __shfl(dl, t + i, 64);                                           \
        rr[i] = ((const unsigned*)((TBL) + (size_t)s * 128))[lane];              \
      }                                                                          \
      _Pragma("unroll")                                                          \
      for (int i = 0; i < 8; i++) {                                              \
        ax += ww[i] * bflo(rr[i]);                                               \
        ay += ww[i] * bfhi(rr[i]);                                               \
      }                                                                          \
    }                                                                            \
    for (; t < m; t++) {                                                         \
      int s = __shfl(sl, t, 64);                                                 \
      float w = __shfl(dl, t, 64);                                               \
      unsigned r = ((const unsigned*)((TBL) + (size_t)s * 128))[lane];           \
      ax += w * bflo(r);                                                         \
      ay += w * bfhi(r);                                                         \
    }                                                                            \
  }

// ---------------- layer-1 aggregate (+bias+relu) ----------------
__global__ __launch_bounds__(256) void k_agg128(const unsigned short* __restrict__ xwb,
                                                const float* __restrict__ dinv,
                                                const int* __restrict__ start,
                                                const int* __restrict__ cnt,
                                                const int* __restrict__ col,
                                                const float* __restrict__ bias,
                                                unsigned short* __restrict__ out, int N) {
  const int lane = threadIdx.x & 63;
  const int v = blockIdx.x * 4 + (threadIdx.x >> 6);
  if (v >= N) return;
  const float dv = dinv[v];
  unsigned u = ((const unsigned*)(xwb + (size_t)v * 128))[lane];
  float ax = dv * dv * bflo(u);
  float ay = dv * dv * bfhi(u);
  const int j0 = start[v], jc = cnt[v];
  GATHER_LOOP(xwb)
  float2 b = ((const float2*)bias)[lane];
  ax = fmaxf(ax + b.x, 0.0f);
  ay = fmaxf(ay + b.y, 0.0f);
  ((unsigned*)(out + (size_t)v * 128))[lane] =
      (unsigned)f2bf(ax) | ((unsigned)f2bf(ay) << 16);
}

// ---------------- second aggregate on h1 fused with pooling (8-way stage) ----------
__global__ __launch_bounds__(256) void k_aggpool128(const unsigned short* __restrict__ h1b,
                                                    const float* __restrict__ dinv,
                                                    const int* __restrict__ start,
                                                    const int* __restrict__ cnt,
                                                    const int* __restrict__ col,
                                                    const int* __restrict__ batch,
                                                    float* __restrict__ stage, int N) {
  __shared__ float2 red[256];
  const int lane = threadIdx.x & 63;
  const int wv = threadIdx.x >> 6;
  const int v = blockIdx.x * 4 + wv;
  float ax = 0.0f, ay = 0.0f;
  if (v < N) {
    const float dv = dinv[v];
    unsigned u = ((const unsigned*)(h1b + (size_t)v * 128))[lane];
    ax = dv * dv * bflo(u);
    ay = dv * dv * bfhi(u);
    const int j0 = start[v], jc = cnt[v];
    GATHER_LOOP(h1b)
  }
  red[threadIdx.x] = make_float2(ax, ay);
  __syncthreads();
  float* st = stage + (size_t)(blockIdx.x & 7) * 64 * 128;  // 8 replicated copies
  const int v0 = blockIdx.x * 4;
  const int b0 = batch[min(v0, N - 1)];
  const int b3 = batch[min(v0 + 3, N - 1)];
  if ((b0 == b3) && (v0 + 3 < N)) {          // sorted batch -> block-uniform graph
    if (wv == 0) {
      float2 r0 = red[lane], r1 = red[64 + lane], r2 = red[128 + lane], r3 = red[192 + lane];
      atomicAdd(&st[b0 * 128 + 2 * lane], r0.x + r1.x + r2.x + r3.x);
      atomicAdd(&st[b0 * 128 + 2 * lane + 1], r0.y + r1.y + r2.y + r3.y);
    }
  } else if (v < N) {
    int b = batch[v];
    atomicAdd(&st[b * 128 + 2 * lane], ax);
    atomicAdd(&st[b * 128 + 2 * lane + 1], ay);
  }
}

// reduce 8 stage copies -> pooled[64*128]
__global__ void k_sreduce(const float* __restrict__ stage, float* __restrict__ pooled) {
  int i = blockIdx.x * 256 + threadIdx.x;  // 8192 total
  float s = 0.0f;
#pragma unroll
  for (int k = 0; k < 8; k++) s += stage[k * 8192 + i];
  pooled[i] = s;
}

// ---------------- final: counts; out = (pooled/n) @ W2 + b2 ----------------
__global__ void k_final(const float* __restrict__ pooled, const int* __restrict__ firstIdx,
                        const float* __restrict__ W2, const float* __restrict__ b2,
                        float* __restrict__ out, int N) {
  __shared__ float rinv[64];
  const int tid = threadIdx.x;
  if (tid < 64) {
    int raw = firstIdx[tid];
    int fi = (raw > 0) ? raw - 1 : 0x7FFFFFFF;
    int m = fi;
#pragma unroll
    for (int d = 1; d < 64; d <<= 1) {
      int t = __shfl_down(m, d, 64);
      if (tid + d < 64) m = min(m, t);
    }
    int nxtm = __shfl_down(m, 1, 64);           // min first-idx over graphs > tid
    int nxt = (tid == 63) ? N : min(nxtm, N);
    int cgt = (fi == 0x7FFFFFFF) ? 0 : (nxt - fi);
    rinv[tid] = 1.0f / fmaxf((float)cgt, 1.0f);
  }
  __syncthreads();
  const int g = tid >> 2;        // 64 graphs
  const int jg = tid & 3;        // 4 groups of 16 outputs
  float acc[16];
#pragma unroll
  for (int i = 0; i < 16; i++) acc[i] = 0.f;
  for (int f = 0; f < 128; f++) {
    float p = pooled[g * 128 + f];
#pragma unroll
    for (int i = 0; i < 16; i++) acc[i] += p * W2[f * 64 + jg * 16 + i];
  }
  float r = rinv[g];
#pragma unroll
  for (int i = 0; i < 16; i++)
    out[g * 64 + jg * 16 + i] = r * acc[i] + b2[jg * 16 + i];
}

// ---------------- launch ----------------

extern "C" void kernel_launch(void* const* d_in, const int* in_sizes, int n_in,
                              void* d_out, int out_size, void* d_ws, size_t ws_size,
                              hipStream_t stream) {
  const float* x     = (const float*)d_in[0];
  const int*   ei    = (const int*)d_in[1];
  const int*   batch = (const int*)d_in[2];
  const float* W1    = (const float*)d_in[3];
  const float* b1    = (const float*)d_in[4];
  const float* W2    = (const float*)d_in[5];
  const float* b2    = (const float*)d_in[6];

  const int N = in_sizes[2];       // 50000
  const int E = in_sizes[1] / 2;   // 800000
  const int* src  = ei;
  const int* dstv = ei + E;

  // workspace layout
  unsigned short* xw1b = (unsigned short*)d_ws;      // N*128 bf16
  unsigned short* h1b  = xw1b + (size_t)N * 128;     // N*128 bf16
  // zero region: cnt[N] counter[1] firstIdx[64] stage[8*64*128]
  int*   cnt      = (int*)(h1b + (size_t)N * 128);
  int*   counter  = cnt + N;
  int*   firstIdx = counter + 1;
  float* stage    = (float*)(firstIdx + 64);         // 8 copies of 64*128
  const size_t zero_ints = (size_t)N + 1 + 64 + 8 * 64 * 128;
  // non-zeroed scratch
  float* pooled   = stage + 8 * 64 * 128;            // 64*128
  int*   startv   = (int*)(pooled + 64 * 128);       // N
  int*   cursor   = startv + N;                      // N
  float* dinv     = (float*)(cursor + N);            // N
  int*   col      = (int*)(dinv + N);                // E
  float* outp     = (float*)d_out;                   // 64*64

  hipMemsetAsync(cnt, 0, zero_ints * sizeof(int), stream);

  const int gM = (N + 63) / 64;     // 782
  const int gE = (E + 255) / 256;   // 3125
  const int gN = (N + 255) / 256;   // 196
  const int gA = (N + 3) / 4;       // 12500
  const int gF = 1024;              // fill blocks inside mega

  k_pre<<<gE + gN, 256, 0, stream>>>(dstv, cnt, E, batch, firstIdx, N, gE);
  k_seg<<<gN, 256, 0, stream>>>(cnt, startv, cursor, dinv, counter, N);

  // GEMM1 overlapped with edge-fill (independent after seg)
  k_mega<<<gM + gF, 256, 0, stream>>>(x, W1, xw1b, N, src, dstv, cursor, col, E, gM);

  // layer 1 aggregate (+bias+relu)
  k_agg128<<<gA, 256, 0, stream>>>(xw1b, dinv, startv, cnt, col, b1, h1b, N);

  // layer 2 commuted: stage[g] = sum_{v in g} Agg(h1)[v]; then (pooled/n) @ W2 + b2
  k_aggpool128<<<gA, 256, 0, stream>>>(h1b, dinv, startv, cnt, col, batch, stage, N);
  k_sreduce<<<32, 256, 0, stream>>>(stage, pooled);
  k_final<<<1, 256, 0, stream>>>(pooled, firstIdx, W2, b2, outp, N);
}

// Round 11
// 308.619 us; speedup vs baseline: 1.1590x; 1.0506x over previous
//
#include <hip/hip_runtime.h>

typedef __attribute__((ext_vector_type(8))) short bf16x8;
typedef __attribute__((ext_vector_type(4))) float f32x4;

__device__ __forceinline__ unsigned short f2bf(float f) {  // RNE
  unsigned u = __float_as_uint(f);
  u += 0x7FFFu + ((u >> 16) & 1u);
  return (unsigned short)(u >> 16);
}
__device__ __forceinline__ float bflo(unsigned u) { return __uint_as_float(u << 16); }
__device__ __forceinline__ float bfhi(unsigned u) { return __uint_as_float(u & 0xFFFF0000u); }

// ---------------- MFMA bf16 GEMM body (m89/m91-verified layouts) ----------------
__device__ __forceinline__ void gemm1_body(const float* __restrict__ A0,
                                           const float* __restrict__ W,
                                           unsigned short* __restrict__ Y, int N,
                                           int bid, int tid, unsigned short* Wl) {
  constexpr int K = 128, CO = 128;
  constexpr int SP = K + 8;
  for (int i = tid; i < K * CO; i += 256) {
    int k = i / CO, n = i % CO;
    Wl[n * SP + k] = f2bf(W[i]);
  }
  __syncthreads();

  const int lane = tid & 63;
  const int quad = lane >> 4, l16 = lane & 15;
  const int mbase = bid * 64 + (tid >> 6) * 16;
  const int arow = min(mbase + l16, N - 1);

  bf16x8 afrag[4];
  const float* A = A0 + (size_t)arow * K;
#pragma unroll
  for (int ks = 0; ks < 4; ks++) {
    const float4* p = (const float4*)(A + ks * 32 + quad * 8);
    float4 f0 = p[0], f1 = p[1];
    afrag[ks] = (bf16x8){(short)f2bf(f0.x), (short)f2bf(f0.y), (short)f2bf(f0.z), (short)f2bf(f0.w),
                         (short)f2bf(f1.x), (short)f2bf(f1.y), (short)f2bf(f1.z), (short)f2bf(f1.w)};
  }

#pragma unroll
  for (int ct = 0; ct < CO / 16; ct++) {
    f32x4 acc = {0.0f, 0.0f, 0.0f, 0.0f};
#pragma unroll
    for (int ks = 0; ks < 4; ks++) {
      bf16x8 b = *(const bf16x8*)(&Wl[(ct * 16 + l16) * SP + ks * 32 + quad * 8]);
      acc = __builtin_amdgcn_mfma_f32_16x16x32_bf16(afrag[ks], b, acc, 0, 0, 0);
    }
#pragma unroll
    for (int reg = 0; reg < 4; reg++) {
      int node = mbase + quad * 4 + reg;
      if (node < N) Y[(size_t)node * CO + ct * 16 + l16] = f2bf(acc[reg]);
    }
  }
}

// ---------------- pre: edge histogram (keeps rank!) | batch first-occurrence --------
__global__ __launch_bounds__(256) void k_pre(const int* __restrict__ dst,
                                             int* __restrict__ cnt,
                                             int* __restrict__ rank, int E,
                                             const int* __restrict__ batch,
                                             int* __restrict__ firstIdx, int N, int gE) {
  const int bid = blockIdx.x, tid = threadIdx.x;
  if (bid < gE) {
    int e = bid * 256 + tid;
    if (e < E) rank[e] = atomicAdd(&cnt[dst[e]], 1);  // rank within dst-segment
  } else {
    int n = (bid - gE) * 256 + tid;
    if (n < N) {
      int b = batch[n];
      if (n == 0 || batch[n - 1] != b) firstIdx[b] = n + 1;  // +1-encoded
    }
  }
}

// ---------------- segment allocation (order-free) ----------------
__global__ void k_seg(const int* __restrict__ cnt, int* __restrict__ start,
                      float* __restrict__ dinv, int* __restrict__ counter, int N) {
  const int v = blockIdx.x * 256 + threadIdx.x;
  const int lane = threadIdx.x & 63;
  int cn = (v < N) ? cnt[v] : 0;
  int incl = cn;
#pragma unroll
  for (int d = 1; d < 64; d <<= 1) {
    int t = __shfl_up(incl, d, 64);
    if (lane >= d) incl += t;
  }
  int base = 0;
  if (lane == 63) base = atomicAdd(counter, incl);
  base = __shfl(base, 63, 64);
  if (v < N) {
    start[v] = base + incl - cn;
    dinv[v] = rsqrtf((float)(cn + 1));  // +1 self-loop
  }
}

// ---------------- mega: GEMM1 blocks || atomic-free edge scatter ----------------
__global__ __launch_bounds__(256) void k_mega(const float* __restrict__ x,
                                              const float* __restrict__ W1,
                                              unsigned short* __restrict__ xw1b, int N,
                                              const int* __restrict__ src,
                                              const int* __restrict__ dst,
                                              const int* __restrict__ rank,
                                              const int* __restrict__ start,
                                              int* __restrict__ col, int E, int gM) {
  __shared__ unsigned short Wl[128 * 136];
  const int bid = blockIdx.x, tid = threadIdx.x;
  if (bid < gM) {
    gemm1_body(x, W1, xw1b, N, bid, tid, Wl);
  } else {
    const int stride = (gridDim.x - gM) * 256;
    for (int e = (bid - gM) * 256 + tid; e < E; e += stride) {
      int d = dst[e];
      col[start[d] + rank[e]] = src[e];  // fire-and-forget scatter, no atomic
    }
  }
}

// ---------------- batched-MLP gather core: 16 row-loads in flight ----------------
#define GATHER_LOOP(TBL)                                                         \
  for (int base = 0; base < jc; base += 64) {                                    \
    int sl = (base + lane < jc) ? col[j0 + base + lane] : 0;                     \
    float dl = dinv[sl] * dv;                                                    \
    const int m = min(64, jc - base);                                            \
    int t = 0;                                                                   \
    for (; t + 16 <= m; t += 16) {                                               \
      unsigned rr[16];                                                           \
      _Pragma("unroll")                                                          \
      for (int i = 0; i < 16; i++) {                                             \
        int s = __shfl(sl, t + i, 64);                                           \
        rr[i] = ((const unsigned*)((TBL) + (size_t)s * 128))[lane];              \
      }                                                                          \
      _Pragma("unroll")                                                          \
      for (int i = 0; i < 16; i++) {                                             \
        float w = __shfl(dl, t + i, 64);                                         \
        ax += w * bflo(rr[i]);                                                   \
        ay += w * bfhi(rr[i]);                                                   \
      }                                                                          \
    }                                                                            \
    for (; t + 8 <= m; t += 8) {                                                 \
      unsigned rr[8];                                                            \
      _Pragma("unroll")                                                          \
      for (int i = 0; i < 8; i++) {                                              \
        int s = __shfl(sl, t + i, 64);                                           \
        rr[i] = ((const unsigned*)((TBL) + (size_t)s * 128))[lane];              \
      }                                                                          \
      _Pragma("unroll")                                                          \
      for (int i = 0; i < 8; i++) {                                              \
        float w = __shfl(dl, t + i, 64);                                         \
        ax += w * bflo(rr[i]);                                                   \
        ay += w * bfhi(rr[i]);                                                   \
      }                                                                          \
    }                                                                            \
    for (; t < m; t++) {                                                         \
      int s = __shfl(sl, t, 64);                                                 \
      float w = __shfl(dl, t, 64);                                               \
      unsigned r = ((const unsigned*)((TBL) + (size_t)s * 128))[lane];           \
      ax += w * bflo(r);                                                         \
      ay += w * bfhi(r);                                                         \
    }                                                                            \
  }

// ---------------- layer-1 aggregate (+bias+relu) ----------------
__global__ __launch_bounds__(256) void k_agg128(const unsigned short* __restrict__ xwb,
                                                const float* __restrict__ dinv,
                                                const int* __restrict__ start,
                                                const int* __restrict__ cnt,
                                                const int* __restrict__ col,
                                                const float* __restrict__ bias,
                                                unsigned short* __restrict__ out, int N) {
  const int lane = threadIdx.x & 63;
  const int v = blockIdx.x * 4 + (threadIdx.x >> 6);
  if (v >= N) return;
  const float dv = dinv[v];
  unsigned u = ((const unsigned*)(xwb + (size_t)v * 128))[lane];
  float ax = dv * dv * bflo(u);
  float ay = dv * dv * bfhi(u);
  const int j0 = start[v], jc = cnt[v];
  GATHER_LOOP(xwb)
  float2 b = ((const float2*)bias)[lane];
  ax = fmaxf(ax + b.x, 0.0f);
  ay = fmaxf(ay + b.y, 0.0f);
  ((unsigned*)(out + (size_t)v * 128))[lane] =
      (unsigned)f2bf(ax) | ((unsigned)f2bf(ay) << 16);
}

// ---------------- second aggregate on h1 fused with pooling (8-way stage) ----------
__global__ __launch_bounds__(256) void k_aggpool128(const unsigned short* __restrict__ h1b,
                                                    const float* __restrict__ dinv,
                                                    const int* __restrict__ start,
                                                    const int* __restrict__ cnt,
                                                    const int* __restrict__ col,
                                                    const int* __restrict__ batch,
                                                    float* __restrict__ stage, int N) {
  __shared__ float2 red[256];
  const int lane = threadIdx.x & 63;
  const int wv = threadIdx.x >> 6;
  const int v = blockIdx.x * 4 + wv;
  float ax = 0.0f, ay = 0.0f;
  if (v < N) {
    const float dv = dinv[v];
    unsigned u = ((const unsigned*)(h1b + (size_t)v * 128))[lane];
    ax = dv * dv * bflo(u);
    ay = dv * dv * bfhi(u);
    const int j0 = start[v], jc = cnt[v];
    GATHER_LOOP(h1b)
  }
  red[threadIdx.x] = make_float2(ax, ay);
  __syncthreads();
  float* st = stage + (size_t)(blockIdx.x & 7) * 64 * 128;  // 8 replicated copies
  const int v0 = blockIdx.x * 4;
  const int b0 = batch[min(v0, N - 1)];
  const int b3 = batch[min(v0 + 3, N - 1)];
  if ((b0 == b3) && (v0 + 3 < N)) {          // sorted batch -> block-uniform graph
    if (wv == 0) {
      float2 r0 = red[lane], r1 = red[64 + lane], r2 = red[128 + lane], r3 = red[192 + lane];
      atomicAdd(&st[b0 * 128 + 2 * lane], r0.x + r1.x + r2.x + r3.x);
      atomicAdd(&st[b0 * 128 + 2 * lane + 1], r0.y + r1.y + r2.y + r3.y);
    }
  } else if (v < N) {
    int b = batch[v];
    atomicAdd(&st[b * 128 + 2 * lane], ax);
    atomicAdd(&st[b * 128 + 2 * lane + 1], ay);
  }
}

// reduce 8 stage copies -> pooled[64*128]
__global__ void k_sreduce(const float* __restrict__ stage, float* __restrict__ pooled) {
  int i = blockIdx.x * 256 + threadIdx.x;  // 8192 total
  float s = 0.0f;
#pragma unroll
  for (int k = 0; k < 8; k++) s += stage[k * 8192 + i];
  pooled[i] = s;
}

// ---------------- final: counts; out = (pooled/n) @ W2 + b2 ----------------
__global__ void k_final(const float* __restrict__ pooled, const int* __restrict__ firstIdx,
                        const float* __restrict__ W2, const float* __restrict__ b2,
                        float* __restrict__ out, int N) {
  __shared__ float rinv[64];
  const int tid = threadIdx.x;
  if (tid < 64) {
    int raw = firstIdx[tid];
    int fi = (raw > 0) ? raw - 1 : 0x7FFFFFFF;
    int m = fi;
#pragma unroll
    for (int d = 1; d < 64; d <<= 1) {
      int t = __shfl_down(m, d, 64);
      if (tid + d < 64) m = min(m, t);
    }
    int nxtm = __shfl_down(m, 1, 64);           // min first-idx over graphs > tid
    int nxt = (tid == 63) ? N : min(nxtm, N);
    int cgt = (fi == 0x7FFFFFFF) ? 0 : (nxt - fi);
    rinv[tid] = 1.0f / fmaxf((float)cgt, 1.0f);
  }
  __syncthreads();
  const int g = tid >> 2;        // 64 graphs
  const int jg = tid & 3;        // 4 groups of 16 outputs
  float acc[16];
#pragma unroll
  for (int i = 0; i < 16; i++) acc[i] = 0.f;
  for (int f = 0; f < 128; f++) {
    float p = pooled[g * 128 + f];
#pragma unroll
    for (int i = 0; i < 16; i++) acc[i] += p * W2[f * 64 + jg * 16 + i];
  }
  float r = rinv[g];
#pragma unroll
  for (int i = 0; i < 16; i++)
    out[g * 64 + jg * 16 + i] = r * acc[i] + b2[jg * 16 + i];
}

// ---------------- launch ----------------

extern "C" void kernel_launch(void* const* d_in, const int* in_sizes, int n_in,
                              void* d_out, int out_size, void* d_ws, size_t ws_size,
                              hipStream_t stream) {
  const float* x     = (const float*)d_in[0];
  const int*   ei    = (const int*)d_in[1];
  const int*   batch = (const int*)d_in[2];
  const float* W1    = (const float*)d_in[3];
  const float* b1    = (const float*)d_in[4];
  const float* W2    = (const float*)d_in[5];
  const float* b2    = (const float*)d_in[6];

  const int N = in_sizes[2];       // 50000
  const int E = in_sizes[1] / 2;   // 800000
  const int* src  = ei;
  const int* dstv = ei + E;

  // workspace layout
  unsigned short* xw1b = (unsigned short*)d_ws;      // N*128 bf16
  unsigned short* h1b  = xw1b + (size_t)N * 128;     // N*128 bf16
  // zero region: cnt[N] counter[1] firstIdx[64] stage[8*64*128]
  int*   cnt      = (int*)(h1b + (size_t)N * 128);
  int*   counter  = cnt + N;
  int*   firstIdx = counter + 1;
  float* stage    = (float*)(firstIdx + 64);         // 8 copies of 64*128
  const size_t zero_ints = (size_t)N + 1 + 64 + 8 * 64 * 128;
  // non-zeroed scratch
  float* pooled   = stage + 8 * 64 * 128;            // 64*128
  int*   startv   = (int*)(pooled + 64 * 128);       // N
  float* dinv     = (float*)(startv + N);            // N
  int*   rank     = (int*)(dinv + N);                // E
  int*   col      = rank + E;                        // E
  float* outp     = (float*)d_out;                   // 64*64

  hipMemsetAsync(cnt, 0, zero_ints * sizeof(int), stream);

  const int gM = (N + 63) / 64;     // 782
  const int gE = (E + 255) / 256;   // 3125
  const int gN = (N + 255) / 256;   // 196
  const int gA = (N + 3) / 4;       // 12500
  const int gF = 1024;              // scatter blocks inside mega

  k_pre<<<gE + gN, 256, 0, stream>>>(dstv, cnt, rank, E, batch, firstIdx, N, gE);
  k_seg<<<gN, 256, 0, stream>>>(cnt, startv, dinv, counter, N);

  // GEMM1 overlapped with atomic-free edge scatter
  k_mega<<<gM + gF, 256, 0, stream>>>(x, W1, xw1b, N, src, dstv, rank, startv, col, E, gM);

  // layer 1 aggregate (+bias+relu)
  k_agg128<<<gA, 256, 0, stream>>>(xw1b, dinv, startv, cnt, col, b1, h1b, N);

  // layer 2 commuted: stage[g] = sum_{v in g} Agg(h1)[v]; then (pooled/n) @ W2 + b2
  k_aggpool128<<<gA, 256, 0, stream>>>(h1b, dinv, startv, cnt, col, batch, stage, N);
  k_sreduce<<<32, 256, 0, stream>>>(stage, pooled);
  k_final<<<1, 256, 0, stream>>>(pooled, firstIdx, W2, b2, outp, N);
}